// Round 1
// baseline (7432.223 us; speedup 1.0000x reference)
//
#include <hip/hip_runtime.h>

#define B_N 256
#define F_N 256
#define NJ3 51
#define DH 512
#define G4 2048
#define CTX 563
#define OUT0 (B_N * F_N * NJ3)   // 3342336
#define CTXOFF OUT0

typedef __attribute__((ext_vector_type(8))) short short8;
typedef __attribute__((ext_vector_type(4))) float floatx4;

__device__ __forceinline__ short f2bf(float f) {
  unsigned u = __float_as_uint(f);
  u = (u + 0x7fffu + ((u >> 16) & 1u)) >> 16;
  return (short)u;
}

// ---------------------------------------------------------------------------
// Generic fp32 tiled GEMM: C = act(A[M,K](lda) @ Bw[K,N] + bias)
// mode 0: relu -> out_f[M,N]
// mode 1: x_emb: write bf16 to out_h0 laid out [F][B][512]  (m = b*256+f)
// mode 2: z3 scatter: n<512 -> h0 bf16, <1024 -> h1 bf16, <1536 -> c0 f32, else c1
// mode 3: preds dual-write: out_f[m*51+n] and out_f2[m*563+512+n]
// ---------------------------------------------------------------------------
__global__ __launch_bounds__(256) void gemm_f32(
    const float* __restrict__ A, int lda,
    const float* __restrict__ Bw, const float* __restrict__ bias,
    int M, int N, int K, int mode,
    float* __restrict__ out_f, float* __restrict__ out_f2,
    short* __restrict__ out_h0, short* __restrict__ out_h1,
    float* __restrict__ out_c0, float* __restrict__ out_c1)
{
  __shared__ float As[16][64];
  __shared__ float Bs[16][68];
  int tid = threadIdx.x;
  int n0 = blockIdx.x * 64, m0 = blockIdx.y * 64;
  float acc[4][4] = {{0.f}};
  int ar = tid >> 2, ak = (tid & 3) * 4;
  int bk = tid >> 6, bn = tid & 63;
  int tm = (tid >> 4) * 4, tn = (tid & 15) * 4;
  for (int k0 = 0; k0 < K; k0 += 16) {
#pragma unroll
    for (int i = 0; i < 4; i++) {
      int kk = ak + i;
      float v = 0.f;
      if (k0 + kk < K) v = A[(long)(m0 + ar) * lda + k0 + kk];
      As[kk][ar] = v;
    }
#pragma unroll
    for (int i = 0; i < 4; i++) {
      int kk = bk + i * 4;
      float v = 0.f;
      if (k0 + kk < K && n0 + bn < N) v = Bw[(long)(k0 + kk) * N + n0 + bn];
      Bs[kk][bn] = v;
    }
    __syncthreads();
#pragma unroll
    for (int kk = 0; kk < 16; kk++) {
      float a0[4], b0[4];
#pragma unroll
      for (int i = 0; i < 4; i++) a0[i] = As[kk][tm + i];
#pragma unroll
      for (int j = 0; j < 4; j++) b0[j] = Bs[kk][tn + j];
#pragma unroll
      for (int i = 0; i < 4; i++)
#pragma unroll
        for (int j = 0; j < 4; j++) acc[i][j] += a0[i] * b0[j];
    }
    __syncthreads();
  }
#pragma unroll
  for (int i = 0; i < 4; i++) {
    int m = m0 + tm + i;
#pragma unroll
    for (int j = 0; j < 4; j++) {
      int n = n0 + tn + j;
      if (n >= N) continue;
      float v = acc[i][j] + bias[n];
      if (mode == 0) {
        out_f[(long)m * N + n] = fmaxf(v, 0.f);
      } else if (mode == 1) {
        int b = m >> 8, f = m & 255;
        out_h0[((long)f * 256 + b) * 512 + n] = f2bf(v);
      } else if (mode == 2) {
        int d = n & 511;
        if (n < 512)       out_h0[m * 512 + d] = f2bf(v);
        else if (n < 1024) out_h1[m * 512 + d] = f2bf(v);
        else if (n < 1536) out_c0[m * 512 + d] = v;
        else               out_c1[m * 512 + d] = v;
      } else {
        out_f[(long)m * NJ3 + n] = v;
        out_f2[(long)m * CTX + 512 + n] = v;
      }
    }
  }
}

// ---------------------------------------------------------------------------
// Pack weights (fp32 -> bf16) into exact MFMA B-fragment layout:
// element index = ((nt*KC + kc)*64 + lane)*8 + j  holds  B[kc*32+(lane>>4)*8+j][nt*16+(lane&15)]
// column j' = 4*d + gate  ->  original gate row jo = gate*512 + d
// mode 0: B0A (t=0): rows [Wih0_x(512) | Whh0(512) | Wih0_pred pad to 64]   K=1088
// mode 1: B0B (t>0): rows [Wih0_x(512) | Whh0(512) | Wfold = dec_W @ Wp^T]  K=1536
// mode 2: B1:        rows [Wih1(512)   | Whh1(512)]                          K=1024
// ---------------------------------------------------------------------------
__global__ __launch_bounds__(256) void pack_b(
    short* __restrict__ dst, int KC, int mode,
    const float* __restrict__ Wih0, const float* __restrict__ Whh0,
    const float* __restrict__ Wih1, const float* __restrict__ Whh1,
    const float* __restrict__ dec_W)
{
  int idx = blockIdx.x * 256 + threadIdx.x;
  int total = KC * 32 * G4;
  if (idx >= total) return;
  int j = idx & 7;
  int l = (idx >> 3) & 63;
  int tt = idx >> 9;
  int kc = tt % KC;
  int nt = tt / KC;
  int k = kc * 32 + ((l >> 4) << 3) + j;
  int jp = nt * 16 + (l & 15);
  int jo = ((jp & 3) << 9) + (jp >> 2);
  float v = 0.f;
  if (mode == 0) {
    if (k < 512) v = Wih0[jo * 563 + k];
    else if (k < 1024) v = Whh0[jo * 512 + k - 512];
    else { int p = k - 1024; v = (p < NJ3) ? Wih0[jo * 563 + 512 + p] : 0.f; }
  } else if (mode == 1) {
    if (k < 512) v = Wih0[jo * 563 + k];
    else if (k < 1024) v = Whh0[jo * 512 + k - 512];
    else {
      int dd = k - 1024;
      float s = 0.f;
      for (int p = 0; p < NJ3; p++) s += dec_W[dd * NJ3 + p] * Wih0[jo * 563 + 512 + p];
      v = s;
    }
  } else {
    if (k < 512) v = Wih1[jo * 512 + k];
    else v = Whh1[jo * 512 + k - 512];
  }
  dst[idx] = f2bf(v);
}

// biases in j'=4d+g order; bias0B includes the dec_b fold; pred0pad bf16 [256][64]
__global__ __launch_bounds__(256) void prep_small(
    float* __restrict__ bias0A, float* __restrict__ bias0B, float* __restrict__ bias1,
    short* __restrict__ pred0pad,
    const float* __restrict__ bih0, const float* __restrict__ bhh0,
    const float* __restrict__ bih1, const float* __restrict__ bhh1,
    const float* __restrict__ Wih0, const float* __restrict__ dec_b,
    const float* __restrict__ init_p)
{
  int i = blockIdx.x * 256 + threadIdx.x;
  if (i < G4) {
    int jo = ((i & 3) << 9) + (i >> 2);
    float b0 = bih0[jo] + bhh0[jo];
    bias0A[i] = b0;
    float s = 0.f;
    for (int p = 0; p < NJ3; p++) s += dec_b[p] * Wih0[jo * 563 + 512 + p];
    bias0B[i] = b0 + s;
    bias1[i] = bih1[jo] + bhh1[jo];
  }
  if (i < 16384) {
    int b = i >> 6, p = i & 63;
    pred0pad[i] = (p < NJ3) ? f2bf(init_p[b * 85 + p]) : (short)0;
  }
}

// ---------------------------------------------------------------------------
// Per-step fused GEMM + LSTM cell. Block = 32 batch x 64 gate-cols (16 d x 4 gates).
// grid 256: ng = (bid&7)+8*((bid>>3)&3) pins each gate-slice to one XCD's L2.
// A is segmented along K: [0,512)->A0, [512,1024)->A1, [1024,kend3)->A2.
// Weights pre-packed in B-fragment layout; epilogue: gates->LDS, cell, h bf16 out
// (+ optional fp32 ctx write for layer 1).
// ---------------------------------------------------------------------------
__global__ __launch_bounds__(256) void step_gemm(
    const short8* __restrict__ Bp, const float* __restrict__ bias,
    const short* __restrict__ A0, const short* __restrict__ A1,
    const short* __restrict__ A2, int lda2,
    int kend3,
    float* __restrict__ c_state, short* __restrict__ h_out,
    float* __restrict__ ctx, int ctx_bstride)
{
  __shared__ float gsm[32][68];
  int tid = threadIdx.x;
  int bid = blockIdx.x;
  int ng = (bid & 7) + (((bid >> 3) & 3) << 3);
  int mt = bid >> 5;
  int m0 = mt * 32, n0 = ng * 64;
  int lane = tid & 63, wid = tid >> 6;
  int m_off = (wid & 1) * 16;
  int wn = wid >> 1;
  int row = m0 + m_off + (lane & 15);
  int kgrp = lane >> 4;
  int KC = kend3 >> 5;
  const short8* bp0 = Bp + (long)(ng * 4 + wn * 2) * KC * 64 + lane;
  const short8* bp1 = bp0 + (long)KC * 64;
  floatx4 acc0 = {0.f, 0.f, 0.f, 0.f}, acc1 = {0.f, 0.f, 0.f, 0.f};
  for (int kc = 0; kc < KC; kc++) {
    int k = kc * 32 + kgrp * 8;
    const short* asrc;
    if (k < 512) asrc = A0 + row * 512 + k;
    else if (k < 1024) asrc = A1 + row * 512 + (k - 512);
    else asrc = A2 + row * lda2 + (k - 1024);
    short8 a = *(const short8*)asrc;
    short8 b0 = bp0[kc * 64];
    short8 b1 = bp1[kc * 64];
    acc0 = __builtin_amdgcn_mfma_f32_16x16x32_bf16(a, b0, acc0, 0, 0, 0);
    acc1 = __builtin_amdgcn_mfma_f32_16x16x32_bf16(a, b1, acc1, 0, 0, 0);
  }
  // C layout (m89): col = lane&15, row = (lane>>4)*4 + r
  int crow = m_off + kgrp * 4;
  int ccol = wn * 32 + (lane & 15);
#pragma unroll
  for (int r = 0; r < 4; r++) {
    gsm[crow + r][ccol] = acc0[r];
    gsm[crow + r][ccol + 16] = acc1[r];
  }
  __syncthreads();
  for (int q = tid; q < 512; q += 256) {
    int bl = q >> 4, dl = q & 15;
    int b = m0 + bl;
    int d = ng * 16 + dl;
    int c0 = dl * 4;
    float gi = gsm[bl][c0 + 0] + bias[n0 + c0 + 0];
    float gf = gsm[bl][c0 + 1] + bias[n0 + c0 + 1];
    float gg = gsm[bl][c0 + 2] + bias[n0 + c0 + 2];
    float go = gsm[bl][c0 + 3] + bias[n0 + c0 + 3];
    float cs = c_state[b * 512 + d];
    float is = 1.f / (1.f + __expf(-gi));
    float fs = 1.f / (1.f + __expf(-gf));
    float os = 1.f / (1.f + __expf(-go));
    float gt = tanhf(gg);
    float cn = fs * cs + is * gt;
    float hn = os * tanhf(cn);
    c_state[b * 512 + d] = cn;
    h_out[b * 512 + d] = f2bf(hn);
    if (ctx) ctx[(long)b * ctx_bstride + d] = hn;
  }
}

extern "C" void kernel_launch(void* const* d_in, const int* in_sizes, int n_in,
                              void* d_out, int out_size, void* d_ws, size_t ws_size,
                              hipStream_t stream)
{
  const float* x       = (const float*)d_in[0];
  const float* init_p  = (const float*)d_in[1];
  const float* embed_W = (const float*)d_in[2];
  const float* embed_b = (const float*)d_in[3];
  const float* ni_W1   = (const float*)d_in[4];
  const float* ni_b1   = (const float*)d_in[5];
  const float* ni_W2   = (const float*)d_in[6];
  const float* ni_b2   = (const float*)d_in[7];
  const float* ni_W3   = (const float*)d_in[8];
  const float* ni_b3   = (const float*)d_in[9];
  const float* Wih0    = (const float*)d_in[10];
  const float* Whh0    = (const float*)d_in[11];
  const float* bih0    = (const float*)d_in[12];
  const float* bhh0    = (const float*)d_in[13];
  const float* Wih1    = (const float*)d_in[14];
  const float* Whh1    = (const float*)d_in[15];
  const float* bih1    = (const float*)d_in[16];
  const float* bhh1    = (const float*)d_in[17];
  const float* dec_W   = (const float*)d_in[18];
  const float* dec_b   = (const float*)d_in[19];
  float* out = (float*)d_out;
  char* ws = (char*)d_ws;

  // workspace layout (all 256B-aligned), total ~87.9 MB
  short* xemb = (short*)(ws + 0);                 // [F][B][512] bf16, 67108864 B
  short* B0A  = (short*)(ws + 67108864);          // 1088*2048*2
  short* B0B  = (short*)(ws + 71565312);          // 1536*2048*2
  short* B1p  = (short*)(ws + 77856768);          // 1024*2048*2
  short* Sh0[2] = { (short*)(ws + 82051072), (short*)(ws + 82575360) };
  short* Sh1[2] = { (short*)(ws + 82313216), (short*)(ws + 82837504) };
  float* c0     = (float*)(ws + 83099648);
  float* c1     = (float*)(ws + 83623936);
  float* bias0A = (float*)(ws + 84148224);
  float* bias0B = (float*)(ws + 84156416);
  float* bias1  = (float*)(ws + 84164608);
  short* pred0pad = (short*)(ws + 84172800);      // [256][64] bf16
  float* z1 = (float*)(ws + 84205568);
  float* z2 = (float*)(ws + 84729856);
  float* z3 = (float*)(ws + 85778432);
  (void)z3; (void)in_sizes; (void)n_in; (void)out_size; (void)ws_size;

  // ---- one-time prep (re-run every call; ws is re-poisoned by harness) ----
  pack_b<<<8704, 256, 0, stream>>>(B0A, 34, 0, Wih0, Whh0, Wih1, Whh1, dec_W);
  pack_b<<<12288, 256, 0, stream>>>(B0B, 48, 1, Wih0, Whh0, Wih1, Whh1, dec_W);
  pack_b<<<8192, 256, 0, stream>>>(B1p, 32, 2, Wih0, Whh0, Wih1, Whh1, dec_W);
  prep_small<<<64, 256, 0, stream>>>(bias0A, bias0B, bias1, pred0pad,
                                     bih0, bhh0, bih1, bhh1, Wih0, dec_b, init_p);
  // x_emb = x @ embed_W + embed_b  -> bf16 [F][B][512]
  gemm_f32<<<dim3(8, 1024), 256, 0, stream>>>(x, 34, embed_W, embed_b,
      65536, 512, 34, 1, nullptr, nullptr, xemb, nullptr, nullptr, nullptr);
  // init MLP: z1 = relu(init@W1+b1); z2 = relu(z1@W2+b2); z3 = z2@W3+b3 -> h/c scatter
  gemm_f32<<<dim3(8, 4), 256, 0, stream>>>(init_p, 85, ni_W1, ni_b1,
      256, 512, 85, 0, z1, nullptr, nullptr, nullptr, nullptr, nullptr);
  gemm_f32<<<dim3(16, 4), 256, 0, stream>>>(z1, 512, ni_W2, ni_b2,
      256, 1024, 512, 0, z2, nullptr, nullptr, nullptr, nullptr, nullptr);
  gemm_f32<<<dim3(32, 4), 256, 0, stream>>>(z2, 1024, ni_W3, ni_b3,
      256, 2048, 1024, 2, nullptr, nullptr, Sh0[0], Sh1[0], c0, c1);

  // ---- sequential scan: 2 fused kernels per step ----
  for (int t = 0; t < 256; t++) {
    int p = t & 1;
    const short* A2 = t ? Sh1[p] : pred0pad;   // fold path (h1_prev) or explicit pred0
    step_gemm<<<256, 256, 0, stream>>>(
        (const short8*)(t ? B0B : B0A), t ? bias0B : bias0A,
        xemb + (long)t * 256 * 512, Sh0[p], A2, t ? 512 : 64,
        t ? 1536 : 1088, c0, Sh0[1 - p], nullptr, 0);
    step_gemm<<<256, 256, 0, stream>>>(
        (const short8*)B1p, bias1,
        Sh0[1 - p], Sh1[p], Sh1[p], 512,
        1024, c1, Sh1[1 - p], out + CTXOFF + (long)t * CTX, 256 * CTX);
  }

  // ---- preds = ctx @ dec_W + dec_b -> pred_kp3d + motion_context[...,512:] ----
  gemm_f32<<<dim3(1, 1024), 256, 0, stream>>>(out + CTXOFF, CTX, dec_W, dec_b,
      65536, NJ3, 512, 3, out, out + CTXOFF, nullptr, nullptr, nullptr, nullptr);
}